// Round 2
// baseline (344.490 us; speedup 1.0000x reference)
//
#include <hip/hip_runtime.h>
#include <hip/hip_cooperative_groups.h>

namespace cg = cooperative_groups;

#define EPSILON 1e-7

constexpr int BLOCKS  = 2048;
constexpr int THREADS = 256;

// Fused single-dispatch kernel (cooperative launch):
//   phase 1: grid-stride stream of pred/truth, per-block partials -> d_ws
//   grid.sync()
//   phase 2: block 0 reduces partials and writes the F1-loss scalar.
//
// Reduction identities (c0 = p<0.5 ? p : 1-p; t in {0,1}):
//   s0 = sum c0 [t==0], s1 = sum c0 [t==1], n1 = count[t==1]
//   class0: tp=s0, fp=s1, fn=n0-s0 ; class1: tp=n1-s1, fp=n0-s0, fn=s1
__global__ __launch_bounds__(THREADS) void f1_fused_kernel(
    const float* __restrict__ pred,
    const int*   __restrict__ truth,
    float*       __restrict__ partial,   // [BLOCKS][3] in d_ws
    float*       __restrict__ out,
    int n4, double n_total)
{
    float s0 = 0.0f, s1 = 0.0f;
    int   c1 = 0;

    const float4* p4 = reinterpret_cast<const float4*>(pred);
    const int4*   t4 = reinterpret_cast<const int4*>(truth);

    int idx    = blockIdx.x * blockDim.x + threadIdx.x;
    int stride = gridDim.x * blockDim.x;

    auto body = [&](int i) {
        float4 p = p4[i];
        int4   t = t4[i];
        float c;
        c = (p.x < 0.5f) ? p.x : 1.0f - p.x; if (t.x) s1 += c; else s0 += c; c1 += t.x;
        c = (p.y < 0.5f) ? p.y : 1.0f - p.y; if (t.y) s1 += c; else s0 += c; c1 += t.y;
        c = (p.z < 0.5f) ? p.z : 1.0f - p.z; if (t.z) s1 += c; else s0 += c; c1 += t.z;
        c = (p.w < 0.5f) ? p.w : 1.0f - p.w; if (t.w) s1 += c; else s0 += c; c1 += t.w;
    };

    int i = idx;
    for (; i + stride < n4; i += 2 * stride) {   // unroll x2: 2 independent 32B load pairs in flight
        body(i);
        body(i + stride);
    }
    for (; i < n4; i += stride) body(i);

    // wave (64-lane) shuffle reduction
    #pragma unroll
    for (int off = 32; off > 0; off >>= 1) {
        s0 += __shfl_down(s0, off);
        s1 += __shfl_down(s1, off);
        c1 += __shfl_down(c1, off);
    }

    __shared__ float ls0[THREADS / 64];
    __shared__ float ls1[THREADS / 64];
    __shared__ int   lc1[THREADS / 64];

    int lane = threadIdx.x & 63;
    int wave = threadIdx.x >> 6;
    if (lane == 0) { ls0[wave] = s0; ls1[wave] = s1; lc1[wave] = c1; }
    __syncthreads();

    if (threadIdx.x == 0) {
        float t0 = 0.0f, t1 = 0.0f; int tc = 0;
        #pragma unroll
        for (int w = 0; w < THREADS / 64; ++w) { t0 += ls0[w]; t1 += ls1[w]; tc += lc1[w]; }
        partial[3 * blockIdx.x + 0] = t0;
        partial[3 * blockIdx.x + 1] = t1;
        partial[3 * blockIdx.x + 2] = (float)tc;   // per-block count exact in f32
        __threadfence();                            // make partials device-visible
    }

    cg::this_grid().sync();

    if (blockIdx.x == 0) {
        double d0 = 0.0, d1 = 0.0, dc = 0.0;
        for (int j = threadIdx.x; j < BLOCKS; j += THREADS) {
            d0 += (double)partial[3 * j + 0];
            d1 += (double)partial[3 * j + 1];
            dc += (double)partial[3 * j + 2];
        }

        #pragma unroll
        for (int off = 32; off > 0; off >>= 1) {
            d0 += __shfl_down(d0, off);
            d1 += __shfl_down(d1, off);
            dc += __shfl_down(dc, off);
        }

        __shared__ double ds0[THREADS / 64];
        __shared__ double ds1[THREADS / 64];
        __shared__ double dsc[THREADS / 64];
        if (lane == 0) { ds0[wave] = d0; ds1[wave] = d1; dsc[wave] = dc; }
        __syncthreads();

        if (threadIdx.x == 0) {
            double S0 = 0.0, S1 = 0.0, C1 = 0.0;
            #pragma unroll
            for (int w = 0; w < THREADS / 64; ++w) { S0 += ds0[w]; S1 += ds1[w]; C1 += dsc[w]; }

            double n1 = C1, n0 = n_total - n1;
            double tp0 = S0,      fp0 = S1,      fn0 = n0 - S0;
            double tp1 = n1 - S1, fp1 = n0 - S0, fn1 = S1;

            double p0 = tp0 / (tp0 + fp0 + EPSILON);
            double r0 = tp0 / (tp0 + fn0 + EPSILON);
            double f0 = 2.0 * p0 * r0 / (p0 + r0 + EPSILON);
            f0 = fmin(fmax(f0, (double)EPSILON), 1.0 - (double)EPSILON);

            double p1 = tp1 / (tp1 + fp1 + EPSILON);
            double r1 = tp1 / (tp1 + fn1 + EPSILON);
            double f1 = 2.0 * p1 * r1 / (p1 + r1 + EPSILON);
            f1 = fmin(fmax(f1, (double)EPSILON), 1.0 - (double)EPSILON);

            out[0] = (float)(1.0 - 0.5 * (f0 + f1));
        }
    }
}

extern "C" void kernel_launch(void* const* d_in, const int* in_sizes, int n_in,
                              void* d_out, int out_size, void* d_ws, size_t ws_size,
                              hipStream_t stream) {
    const float* pred    = (const float*)d_in[0];
    const int*   truth   = (const int*)d_in[1];
    float*       out     = (float*)d_out;
    float*       partial = (float*)d_ws;   // BLOCKS*3 floats = 24 KiB

    int    n       = in_sizes[0];
    int    n4      = n / 4;                // N = 2^25, divisible by 4
    double n_total = (double)n;

    void* args[] = { (void*)&pred, (void*)&truth, (void*)&partial, (void*)&out,
                     (void*)&n4, (void*)&n_total };
    hipLaunchCooperativeKernel((void*)f1_fused_kernel, dim3(BLOCKS), dim3(THREADS),
                               args, 0, stream);
}

// Round 3
// 141.942 us; speedup vs baseline: 2.4270x; 2.4270x over previous
//
#include <hip/hip_runtime.h>

#define EPSILON 1e-7

constexpr int BLOCKS  = 2048;
constexpr int THREADS = 256;

// Fixed-point scale for deterministic (order-independent) atomic accumulation.
// Per-block float sums are <= 8192 (16384 elems * 0.5); 8192 * 2^38 = 2^51,
// * 2048 blocks = 2^62 < 2^64. Quantization ~2^-38 relative: negligible.
#define FP_SCALE 274877906944.0f   // 2^38

struct Accum {
    unsigned long long s0;     // sum c0 where t==0, scaled by 2^38
    unsigned long long s1;     // sum c0 where t==1, scaled by 2^38
    unsigned long long n1;     // count of t==1
    unsigned int       ticket; // block completion counter
};

// Single dispatch: grid-stride stream -> per-block partials -> device atomics;
// the last block to finish computes the F1-loss scalar.
//   c0 = p < 0.5 ? p : 1-p
//   class0: tp=s0, fp=s1, fn=n0-s0 ; class1: tp=n1-s1, fp=n0-s0, fn=s1
__global__ __launch_bounds__(THREADS) void f1_onepass_kernel(
    const float* __restrict__ pred,
    const int*   __restrict__ truth,
    Accum*       __restrict__ acc,
    float*       __restrict__ out,
    int n4, double n_total)
{
    float s0 = 0.0f, s1 = 0.0f;
    int   c1 = 0;

    const float4* p4 = reinterpret_cast<const float4*>(pred);
    const int4*   t4 = reinterpret_cast<const int4*>(truth);

    int idx    = blockIdx.x * blockDim.x + threadIdx.x;
    int stride = gridDim.x * blockDim.x;

    for (int i = idx; i < n4; i += stride) {
        float4 p = p4[i];
        int4   t = t4[i];
        float c;
        c = (p.x < 0.5f) ? p.x : 1.0f - p.x; if (t.x) s1 += c; else s0 += c; c1 += t.x;
        c = (p.y < 0.5f) ? p.y : 1.0f - p.y; if (t.y) s1 += c; else s0 += c; c1 += t.y;
        c = (p.z < 0.5f) ? p.z : 1.0f - p.z; if (t.z) s1 += c; else s0 += c; c1 += t.z;
        c = (p.w < 0.5f) ? p.w : 1.0f - p.w; if (t.w) s1 += c; else s0 += c; c1 += t.w;
    }

    // wave (64-lane) shuffle reduction
    #pragma unroll
    for (int off = 32; off > 0; off >>= 1) {
        s0 += __shfl_down(s0, off);
        s1 += __shfl_down(s1, off);
        c1 += __shfl_down(c1, off);
    }

    __shared__ float ls0[THREADS / 64];
    __shared__ float ls1[THREADS / 64];
    __shared__ int   lc1[THREADS / 64];

    int lane = threadIdx.x & 63;
    int wave = threadIdx.x >> 6;
    if (lane == 0) { ls0[wave] = s0; ls1[wave] = s1; lc1[wave] = c1; }
    __syncthreads();

    if (threadIdx.x == 0) {
        float t0 = 0.0f, t1 = 0.0f; int tc = 0;
        #pragma unroll
        for (int w = 0; w < THREADS / 64; ++w) { t0 += ls0[w]; t1 += ls1[w]; tc += lc1[w]; }

        // Deterministic fixed-point accumulation (order-independent).
        atomicAdd(&acc->s0, (unsigned long long)llrintf(t0 * FP_SCALE));
        atomicAdd(&acc->s1, (unsigned long long)llrintf(t1 * FP_SCALE));
        atomicAdd(&acc->n1, (unsigned long long)tc);

        __threadfence();   // value-adds happen-before my ticket increment
        unsigned int prev = atomicAdd(&acc->ticket, 1u);

        if (prev == (unsigned int)(BLOCKS - 1)) {
            // All blocks' value-adds are complete and device-visible.
            __threadfence();
            unsigned long long us0 = __hip_atomic_load(&acc->s0, __ATOMIC_RELAXED, __HIP_MEMORY_SCOPE_AGENT);
            unsigned long long us1 = __hip_atomic_load(&acc->s1, __ATOMIC_RELAXED, __HIP_MEMORY_SCOPE_AGENT);
            unsigned long long un1 = __hip_atomic_load(&acc->n1, __ATOMIC_RELAXED, __HIP_MEMORY_SCOPE_AGENT);

            double S0 = (double)us0 / (double)FP_SCALE;
            double S1 = (double)us1 / (double)FP_SCALE;
            double n1 = (double)un1;
            double n0 = n_total - n1;

            double tp0 = S0,      fp0 = S1,      fn0 = n0 - S0;
            double tp1 = n1 - S1, fp1 = n0 - S0, fn1 = S1;

            double p0 = tp0 / (tp0 + fp0 + EPSILON);
            double r0 = tp0 / (tp0 + fn0 + EPSILON);
            double f0 = 2.0 * p0 * r0 / (p0 + r0 + EPSILON);
            f0 = fmin(fmax(f0, (double)EPSILON), 1.0 - (double)EPSILON);

            double p1 = tp1 / (tp1 + fp1 + EPSILON);
            double r1 = tp1 / (tp1 + fn1 + EPSILON);
            double f1 = 2.0 * p1 * r1 / (p1 + r1 + EPSILON);
            f1 = fmin(fmax(f1, (double)EPSILON), 1.0 - (double)EPSILON);

            out[0] = (float)(1.0 - 0.5 * (f0 + f1));
        }
    }
}

extern "C" void kernel_launch(void* const* d_in, const int* in_sizes, int n_in,
                              void* d_out, int out_size, void* d_ws, size_t ws_size,
                              hipStream_t stream) {
    const float* pred  = (const float*)d_in[0];
    const int*   truth = (const int*)d_in[1];
    float*       out   = (float*)d_out;
    Accum*       acc   = (Accum*)d_ws;

    int    n       = in_sizes[0];
    int    n4      = n / 4;                // N = 2^25, divisible by 4
    double n_total = (double)n;

    // ws is poisoned once (0xAA) and never re-poisoned between replays:
    // zero the accumulator block every call (graph-capture-legal).
    hipMemsetAsync(d_ws, 0, sizeof(Accum), stream);

    f1_onepass_kernel<<<BLOCKS, THREADS, 0, stream>>>(pred, truth, acc, out, n4, n_total);
}

// Round 4
// 49.388 us; speedup vs baseline: 6.9751x; 2.8740x over previous
//
#include <hip/hip_runtime.h>

#define EPSILON 1e-7

constexpr int BLOCKS  = 2048;
constexpr int THREADS = 256;

// Stage 1: per-block partial sums of {s0, s1, n1}
//   c0 = p < 0.5 ? p : 1-p
//   s0 = sum of c0 where t==0, s1 = sum of c0 where t==1, n1 = count of t==1
// Grid-stride with manual x2 unroll: two independent 32B load pairs in flight.
__global__ __launch_bounds__(THREADS) void f1_partial_kernel(
    const float* __restrict__ pred,
    const int*   __restrict__ truth,
    float*       __restrict__ partial,   // [BLOCKS][3]
    int n4)                              // number of 4-element chunks
{
    float s0 = 0.0f, s1 = 0.0f;
    int   c1 = 0;

    const float4* p4 = reinterpret_cast<const float4*>(pred);
    const int4*   t4 = reinterpret_cast<const int4*>(truth);

    int idx    = blockIdx.x * blockDim.x + threadIdx.x;
    int stride = gridDim.x * blockDim.x;

    int i = idx;
    for (; i + stride < n4; i += 2 * stride) {
        // issue all 4 vector loads before consuming any
        float4 pa = p4[i];
        int4   ta = t4[i];
        float4 pb = p4[i + stride];
        int4   tb = t4[i + stride];
        float c;
        c = (pa.x < 0.5f) ? pa.x : 1.0f - pa.x; if (ta.x) s1 += c; else s0 += c; c1 += ta.x;
        c = (pa.y < 0.5f) ? pa.y : 1.0f - pa.y; if (ta.y) s1 += c; else s0 += c; c1 += ta.y;
        c = (pa.z < 0.5f) ? pa.z : 1.0f - pa.z; if (ta.z) s1 += c; else s0 += c; c1 += ta.z;
        c = (pa.w < 0.5f) ? pa.w : 1.0f - pa.w; if (ta.w) s1 += c; else s0 += c; c1 += ta.w;
        c = (pb.x < 0.5f) ? pb.x : 1.0f - pb.x; if (tb.x) s1 += c; else s0 += c; c1 += tb.x;
        c = (pb.y < 0.5f) ? pb.y : 1.0f - pb.y; if (tb.y) s1 += c; else s0 += c; c1 += tb.y;
        c = (pb.z < 0.5f) ? pb.z : 1.0f - pb.z; if (tb.z) s1 += c; else s0 += c; c1 += tb.z;
        c = (pb.w < 0.5f) ? pb.w : 1.0f - pb.w; if (tb.w) s1 += c; else s0 += c; c1 += tb.w;
    }
    for (; i < n4; i += stride) {
        float4 p = p4[i];
        int4   t = t4[i];
        float c;
        c = (p.x < 0.5f) ? p.x : 1.0f - p.x; if (t.x) s1 += c; else s0 += c; c1 += t.x;
        c = (p.y < 0.5f) ? p.y : 1.0f - p.y; if (t.y) s1 += c; else s0 += c; c1 += t.y;
        c = (p.z < 0.5f) ? p.z : 1.0f - p.z; if (t.z) s1 += c; else s0 += c; c1 += t.z;
        c = (p.w < 0.5f) ? p.w : 1.0f - p.w; if (t.w) s1 += c; else s0 += c; c1 += t.w;
    }

    // wave (64-lane) shuffle reduction
    #pragma unroll
    for (int off = 32; off > 0; off >>= 1) {
        s0 += __shfl_down(s0, off);
        s1 += __shfl_down(s1, off);
        c1 += __shfl_down(c1, off);
    }

    __shared__ float ls0[THREADS / 64];
    __shared__ float ls1[THREADS / 64];
    __shared__ int   lc1[THREADS / 64];

    int lane = threadIdx.x & 63;
    int wave = threadIdx.x >> 6;
    if (lane == 0) { ls0[wave] = s0; ls1[wave] = s1; lc1[wave] = c1; }
    __syncthreads();

    if (threadIdx.x == 0) {
        float t0 = 0.0f, t1 = 0.0f; int tc = 0;
        #pragma unroll
        for (int w = 0; w < THREADS / 64; ++w) { t0 += ls0[w]; t1 += ls1[w]; tc += lc1[w]; }
        partial[3 * blockIdx.x + 0] = t0;
        partial[3 * blockIdx.x + 1] = t1;
        partial[3 * blockIdx.x + 2] = (float)tc;   // per-block count exact in f32
    }
}

// Stage 2: reduce per-block partials, compute F1 loss scalar
__global__ __launch_bounds__(THREADS) void f1_final_kernel(
    const float* __restrict__ partial,
    float*       __restrict__ out,
    int nblocks, double n_total)
{
    double s0 = 0.0, s1 = 0.0, c1 = 0.0;
    for (int i = threadIdx.x; i < nblocks; i += blockDim.x) {
        s0 += (double)partial[3 * i + 0];
        s1 += (double)partial[3 * i + 1];
        c1 += (double)partial[3 * i + 2];
    }

    #pragma unroll
    for (int off = 32; off > 0; off >>= 1) {
        s0 += __shfl_down(s0, off);
        s1 += __shfl_down(s1, off);
        c1 += __shfl_down(c1, off);
    }

    __shared__ double ds0[THREADS / 64];
    __shared__ double ds1[THREADS / 64];
    __shared__ double dc1[THREADS / 64];

    int lane = threadIdx.x & 63;
    int wave = threadIdx.x >> 6;
    if (lane == 0) { ds0[wave] = s0; ds1[wave] = s1; dc1[wave] = c1; }
    __syncthreads();

    if (threadIdx.x == 0) {
        double S0 = 0.0, S1 = 0.0, C1 = 0.0;
        #pragma unroll
        for (int w = 0; w < THREADS / 64; ++w) { S0 += ds0[w]; S1 += ds1[w]; C1 += dc1[w]; }

        double n1 = C1, n0 = n_total - n1;
        // class 0: tp=S0, fp=S1, fn=n0-S0
        // class 1: tp=n1-S1, fp=n0-S0, fn=S1
        double tp0 = S0,      fp0 = S1,      fn0 = n0 - S0;
        double tp1 = n1 - S1, fp1 = n0 - S0, fn1 = S1;

        double p0 = tp0 / (tp0 + fp0 + EPSILON);
        double r0 = tp0 / (tp0 + fn0 + EPSILON);
        double f0 = 2.0 * p0 * r0 / (p0 + r0 + EPSILON);
        f0 = fmin(fmax(f0, (double)EPSILON), 1.0 - (double)EPSILON);

        double p1 = tp1 / (tp1 + fp1 + EPSILON);
        double r1 = tp1 / (tp1 + fn1 + EPSILON);
        double f1 = 2.0 * p1 * r1 / (p1 + r1 + EPSILON);
        f1 = fmin(fmax(f1, (double)EPSILON), 1.0 - (double)EPSILON);

        out[0] = (float)(1.0 - 0.5 * (f0 + f1));
    }
}

extern "C" void kernel_launch(void* const* d_in, const int* in_sizes, int n_in,
                              void* d_out, int out_size, void* d_ws, size_t ws_size,
                              hipStream_t stream) {
    const float* pred    = (const float*)d_in[0];
    const int*   truth   = (const int*)d_in[1];
    float*       out     = (float*)d_out;
    float*       partial = (float*)d_ws;   // BLOCKS*3 floats = 24 KiB

    int n  = in_sizes[0];
    int n4 = n / 4;                        // N = 2^25, divisible by 4

    f1_partial_kernel<<<BLOCKS, THREADS, 0, stream>>>(pred, truth, partial, n4);
    f1_final_kernel<<<1, THREADS, 0, stream>>>(partial, out, BLOCKS, (double)n);
}